// Round 2
// baseline (539.091 us; speedup 1.0000x reference)
//
#include <hip/hip_runtime.h>
#include <hip/hip_bf16.h>

#define HH 256
#define WW 256
#define HW 65536
#define NOUT 81     // 9 mask + 4*18 off
#define NFEAT 192   // 144 patch + 48 passthrough

// ---------------------------------------------------------------------------
// Setup: collapse (conv3x3 -> 1x1) into a single 192->81 linear map.
// Wt layout: [f][o], f = p*16+c (p=ky*3+kx patch pos, c in-channel) for f<144,
//            f-144 = passthrough channel (x[16+cr]); o: 0..8 mask k, 9.. = 9+i*18+j.
// bias[o] folds mask_b / off_b and the POINTS*(2i+1) base offsets.
// ---------------------------------------------------------------------------
__global__ __launch_bounds__(256) void setup_weights(
    const float* __restrict__ off_pconv_w,  // (4,16,16,3,3)
    const float* __restrict__ off_w,        // (4,18,64)
    const float* __restrict__ off_b,        // (4,18)
    const float* __restrict__ mask_pconv_w, // (16,16,3,3)
    const float* __restrict__ mask_w,       // (9,64)
    const float* __restrict__ mask_b,       // (9,)
    float* __restrict__ Wt,                 // (192,81)
    float* __restrict__ bias)               // (81,)
{
    int id = blockIdx.x * 256 + threadIdx.x;
    const float PTS[18] = {-1,-1, -1,0, -1,1, 0,-1, 0,0, 0,1, 1,-1, 1,0, 1,1};
    if (id < NFEAT * NOUT) {
        int f = id / NOUT;
        int o = id % NOUT;
        float v;
        if (f < 144) {
            int p = f >> 4, c = f & 15;
            float s = 0.f;
            if (o < 9) {
                for (int cm = 0; cm < 16; ++cm)
                    s += mask_w[o * 64 + cm] * mask_pconv_w[(cm * 16 + c) * 9 + p];
            } else {
                int oo = o - 9, i = oo / 18, j = oo % 18;
                for (int cm = 0; cm < 16; ++cm)
                    s += off_w[(i * 18 + j) * 64 + cm] * off_pconv_w[((i * 16 + cm) * 16 + c) * 9 + p];
            }
            v = s;
        } else {
            int c = f - 144;
            if (o < 9) v = mask_w[o * 64 + 16 + c];
            else { int oo = o - 9, i = oo / 18, j = oo % 18; v = off_w[(i * 18 + j) * 64 + 16 + c]; }
        }
        Wt[id] = v;
    } else if (id < NFEAT * NOUT + NOUT) {
        int o = id - NFEAT * NOUT;
        float v;
        if (o < 9) v = mask_b[o];
        else {
            int oo = o - 9, i = oo / 18, j = oo % 18;
            v = off_b[i * 18 + j] + PTS[j] * (float)(2 * i + 1);
        }
        bias[o] = v;
    }
}

// ---------------------------------------------------------------------------
// Kernel 1: per-pixel 192-feature x 81-output linear map (the fused convs).
// Writes mask (b,9,H,W) and off (b,4,18,H,W) as f32 into workspace.
// ---------------------------------------------------------------------------
__global__ __launch_bounds__(256) void conv_offsets(
    const float* __restrict__ x,     // (2,64,256,256)
    const float* __restrict__ Wt,    // (192,81)
    const float* __restrict__ bias,  // (81,)
    float* __restrict__ mask_ws,     // (2,9,HW)
    float* __restrict__ off_ws)      // (2,72,HW)
{
    int gid = blockIdx.x * 256 + threadIdx.x;   // 131072 threads
    int b = gid >> 16;
    int pix = gid & 65535;
    int h = pix >> 8, w = pix & 255;

    float acc[NOUT];
#pragma unroll
    for (int o = 0; o < NOUT; ++o) acc[o] = bias[o];

    const float* xb = x + (size_t)b * 64 * HW;

    // 3x3 patch over first 16 channels (zero padding)
    for (int p = 0; p < 9; ++p) {
        int hh = h + p / 3 - 1;
        int ww = w + p % 3 - 1;
        bool valid = ((unsigned)hh < 256u) && ((unsigned)ww < 256u);
        int poff = hh * 256 + ww;
        const float* wbase = Wt + p * 16 * NOUT;
        for (int c = 0; c < 16; ++c) {
            float xv = 0.f;
            if (valid) xv = xb[c * HW + poff];
            const float* wr = wbase + c * NOUT;
#pragma unroll
            for (int o = 0; o < NOUT; ++o) acc[o] = fmaf(xv, wr[o], acc[o]);
        }
    }
    // passthrough channels 16..63
    for (int c = 0; c < 48; ++c) {
        float xv = xb[(16 + c) * HW + pix];
        const float* wr = Wt + (144 + c) * NOUT;
#pragma unroll
        for (int o = 0; o < NOUT; ++o) acc[o] = fmaf(xv, wr[o], acc[o]);
    }

#pragma unroll
    for (int k = 0; k < 9; ++k)
        mask_ws[(b * 9 + k) * HW + pix] = acc[k];
#pragma unroll
    for (int t = 0; t < 72; ++t)
        off_ws[(b * 72 + t) * HW + pix] = acc[9 + t];
}

// ---------------------------------------------------------------------------
// Kernel 2: bilinear warp (border clamp) of y1/y2 group slices, * mask, write out.
// grid: (h=256, k=9, z=8 [xb*4+i]); block: 256 (=w). Each thread does 16 ch x 2 tensors.
// ---------------------------------------------------------------------------
__global__ __launch_bounds__(256) void warp_apply(
    const float* __restrict__ y,        // (4,64,256,256)
    const float* __restrict__ mask_ws,  // (2,9,HW)
    const float* __restrict__ off_ws,   // (2,72,HW)
    float* __restrict__ out)            // (4,64,9,256,256)
{
    int w = threadIdx.x;
    int h = blockIdx.x;
    int k = blockIdx.y;
    int z = blockIdx.z;           // xb*4 + i
    int xb = z >> 2, i = z & 3;
    int pix = h * 256 + w;

    float ox = off_ws[(size_t)(z * 18 + 2 * k) * HW + pix];
    float oy = off_ws[(size_t)(z * 18 + 2 * k + 1) * HW + pix];
    float m  = mask_ws[(size_t)(xb * 9 + k) * HW + pix];

    float px = fminf(fmaxf((float)w + ox, 0.f), 255.f);
    float py = fminf(fmaxf((float)h + oy, 0.f), 255.f);
    float x0f = floorf(px), y0f = floorf(py);
    float wx = px - x0f, wy = py - y0f;
    int x0 = (int)x0f, y0 = (int)y0f;
    int x1 = min(x0 + 1, 255), y1 = min(y0 + 1, 255);

    float w00 = (1.f - wx) * (1.f - wy) * m;
    float w01 = wx * (1.f - wy) * m;
    float w10 = (1.f - wx) * wy * m;
    float w11 = wx * wy * m;

    int o00 = y0 * 256 + x0, o01 = y0 * 256 + x1;
    int o10 = y1 * 256 + x0, o11 = y1 * 256 + x1;

    const float* p1 = y + (size_t)(xb * 64 + i * 16) * HW;
    const float* p2 = y + (size_t)((xb + 2) * 64 + i * 16) * HW;
    float* out1 = out + ((size_t)(xb * 64 + i * 16) * 9 + k) * HW + pix;
    float* out2 = out + ((size_t)((xb + 2) * 64 + i * 16) * 9 + k) * HW + pix;

#pragma unroll
    for (int c = 0; c < 16; ++c) {
        const float* q = p1 + (size_t)c * HW;
        float v = w00 * q[o00] + w01 * q[o01] +
                  w10 * q[o10] + w11 * q[o11];
        out1[(size_t)c * 9 * HW] = v;

        q = p2 + (size_t)c * HW;
        v = w00 * q[o00] + w01 * q[o01] +
            w10 * q[o10] + w11 * q[o11];
        out2[(size_t)c * 9 * HW] = v;
    }
}

// ---------------------------------------------------------------------------
extern "C" void kernel_launch(void* const* d_in, const int* in_sizes, int n_in,
                              void* d_out, int out_size, void* d_ws, size_t ws_size,
                              hipStream_t stream) {
    const float* x            = (const float*)d_in[0];
    const float* y            = (const float*)d_in[1];
    const float* off_pconv_w  = (const float*)d_in[2];
    const float* off_w        = (const float*)d_in[3];
    const float* off_b        = (const float*)d_in[4];
    const float* mask_pconv_w = (const float*)d_in[5];
    const float* mask_w       = (const float*)d_in[6];
    const float* mask_b       = (const float*)d_in[7];
    float* out = (float*)d_out;

    // workspace layout (f32): Wt[192*81], bias[81] in first 64KB;
    // mask (2*9*HW) then off (2*72*HW). Total ~42.6 MB.
    float* Wt      = (float*)d_ws;
    float* bias    = Wt + NFEAT * NOUT;
    float* mask_ws = (float*)((char*)d_ws + 65536);
    float* off_ws  = mask_ws + 2 * 9 * HW;

    setup_weights<<<62, 256, 0, stream>>>(off_pconv_w, off_w, off_b,
                                          mask_pconv_w, mask_w, mask_b, Wt, bias);
    conv_offsets<<<512, 256, 0, stream>>>(x, Wt, bias, mask_ws, off_ws);
    dim3 g2(HH, 9, 8);
    warp_apply<<<g2, 256, 0, stream>>>(y, mask_ws, off_ws, out);
}